// Round 3
// baseline (1241.413 us; speedup 1.0000x reference)
//
#include <hip/hip_runtime.h>
#include <hip/hip_bf16.h>

// Problem constants
#define E_ 16
#define H_ 2048
#define I_ 1408
#define TWOI_ 2816
#define K_ 2
#define T_ 8192
#define TK_ 16384   // T_*K_

// per-XCD schedule capacities (32 x-tiles per XCD is ~100 sigma above uniform)
#define CAP1 (32 * 22)   // GEMM1: ny=22
#define CAP2 (32 * 16)   // GEMM2: ny=16

typedef unsigned short ushort_t;
typedef unsigned int uint_t;
typedef short short8 __attribute__((ext_vector_type(8)));
typedef float f32x4 __attribute__((ext_vector_type(4)));

#define AS1 __attribute__((address_space(1)))
#define AS3 __attribute__((address_space(3)))

__device__ __forceinline__ void gl2lds16(const ushort_t* g, ushort_t* l) {
    __builtin_amdgcn_global_load_lds((const AS1 uint_t*)g, (AS3 uint_t*)l, 16, 0, 0);
}

__device__ __forceinline__ ushort_t f2bf(float f) {
    uint_t u = __float_as_uint(f);
    u += 0x7fffu + ((u >> 16) & 1u);   // round-to-nearest-even
    return (ushort_t)(u >> 16);
}
__device__ __forceinline__ uint_t pack2(float a, float b) {
    return (uint_t)f2bf(a) | ((uint_t)f2bf(b) << 16);
}
__device__ __forceinline__ float bflo(uint_t v) { return __uint_as_float(v << 16); }
__device__ __forceinline__ float bfhi(uint_t v) { return __uint_as_float(v & 0xffff0000u); }

// ---------------------------------------------------------------------------
// Routing: bucket slots by expert (wave-aggregated atomics), build per-XCD
// block schedules. sched entry = (e, row0, by, mrows); e=-1 -> no-op block.
// Expert e pinned to XCD e%8; within XCD: expert-major, x-groups of 4, y-sweep.
// ---------------------------------------------------------------------------
__global__ void routing_kernel(const int* __restrict__ idx32,
                               int* __restrict__ token_ids,
                               int* __restrict__ row_of_slot,
                               int4* __restrict__ sched1,
                               int4* __restrict__ sched2) {
    __shared__ int s_cnt[E_], s_off[E_ + 1], s_cur[E_], s_orodd;
    const int tid = threadIdx.x;
    const int lane = tid & 63;
    if (tid < E_) { s_cnt[tid] = 0; s_cur[tid] = 0; }
    if (tid == 0) s_orodd = 0;
    __syncthreads();
    // int64 vs int32 detection: if input is int64, odd 32-bit words are all 0.
    int ao = 0;
    for (int s = tid; s < TK_ / 2; s += (int)blockDim.x) ao |= idx32[2 * s + 1];
    atomicOr(&s_orodd, ao);
    __syncthreads();
    const bool is64 = (s_orodd == 0);
    // count, wave-aggregated
    for (int s0 = 0; s0 < TK_; s0 += (int)blockDim.x) {
        const int s = s0 + tid;
        const int e = is64 ? idx32[2 * s] : idx32[s];
#pragma unroll
        for (int ee = 0; ee < E_; ee++) {
            unsigned long long mask = __ballot(e == ee);
            if (mask && lane == (__ffsll((long long)mask) - 1))
                atomicAdd(&s_cnt[ee], __popcll(mask));
        }
    }
    __syncthreads();
    if (tid == 0) {
        int acc = 0;
        for (int e = 0; e < E_; e++) { s_off[e] = acc; acc += s_cnt[e]; }
        s_off[E_] = acc;
    }
    __syncthreads();
    // build per-XCD schedules (threads 0..7, one per XCD)
    if (tid < 8) {
        const int xcd = tid;
        int j1 = 0, j2 = 0;
#pragma unroll
        for (int pe = 0; pe < 2; pe++) {
            const int e = xcd + 8 * pe;
            const int r0 = s_off[e];
            const int cnt = s_off[e + 1] - s_off[e];
            const int nx = (cnt + 127) >> 7;
            for (int xg = 0; xg < nx; xg += 4) {
                const int gsz = min(4, nx - xg);
                for (int by = 0; by < TWOI_ / 128; by++)
                    for (int xi = 0; xi < gsz; xi++) {
                        const int x = xg + xi;
                        if (j1 < CAP1)
                            sched1[(j1++) * 8 + xcd] =
                                make_int4(e, r0 + x * 128, by, min(128, cnt - x * 128));
                    }
            }
            for (int xg = 0; xg < nx; xg += 4) {
                const int gsz = min(4, nx - xg);
                for (int by = 0; by < H_ / 128; by++)
                    for (int xi = 0; xi < gsz; xi++) {
                        const int x = xg + xi;
                        if (j2 < CAP2)
                            sched2[(j2++) * 8 + xcd] =
                                make_int4(e, r0 + x * 128, by, min(128, cnt - x * 128));
                    }
            }
        }
        for (; j1 < CAP1; j1++) sched1[j1 * 8 + xcd] = make_int4(-1, 0, 0, 0);
        for (; j2 < CAP2; j2++) sched2[j2 * 8 + xcd] = make_int4(-1, 0, 0, 0);
    }
    // placement, wave-aggregated positions
    for (int s0 = 0; s0 < TK_; s0 += (int)blockDim.x) {
        const int s = s0 + tid;
        const int e = is64 ? idx32[2 * s] : idx32[s];
#pragma unroll
        for (int ee = 0; ee < E_; ee++) {
            const bool m = (e == ee);
            unsigned long long mask = __ballot(m);
            if (!mask) continue;
            const int leader = __ffsll((long long)mask) - 1;
            int base = 0;
            if (lane == leader) base = atomicAdd(&s_cur[ee], __popcll(mask));
            base = __shfl(base, leader);
            if (m) {
                const int pos = __popcll(mask & ((1ull << lane) - 1ull));
                const int r = s_off[ee] + base + pos;
                token_ids[r] = s >> 1;   // token = s / K_
                row_of_slot[s] = r;
            }
        }
    }
}

// ---------------------------------------------------------------------------
// fp32 -> bf16 bulk conversion, 8 elements/thread, 16B stores
// ---------------------------------------------------------------------------
__global__ void f2bf_kernel(const float* __restrict__ src, ushort_t* __restrict__ dst, int n8) {
    int i = blockIdx.x * blockDim.x + threadIdx.x;
    const int stride = gridDim.x * blockDim.x;
    for (; i < n8; i += stride) {
        const float4* s = (const float4*)src + 2 * (size_t)i;
        float4 a = s[0], b = s[1];
        uint4 o;
        o.x = pack2(a.x, a.y);
        o.y = pack2(a.z, a.w);
        o.z = pack2(b.x, b.y);
        o.w = pack2(b.z, b.w);
        ((uint4*)dst)[i] = o;
    }
}

// ---------------------------------------------------------------------------
// w_gu fp32 -> bf16 with gate/up row interleave (16-row blocks):
// even nt sub-tiles hold gate, odd nt hold up, pair in the SAME lane.
// ---------------------------------------------------------------------------
__global__ void f2bf_gu_kernel(const float* __restrict__ src, ushort_t* __restrict__ dst) {
    const int PER_E = TWOI_ * (H_ / 8);
    const int n8 = E_ * PER_E;
    int i = blockIdx.x * blockDim.x + threadIdx.x;
    const int stride = gridDim.x * blockDim.x;
    for (; i < n8; i += stride) {
        int e = i / PER_E;
        int rem = i % PER_E;
        int r = rem / (H_ / 8);
        int cg = rem % (H_ / 8);
        int pr;
        if (r < I_) pr = 32 * (r >> 4) + (r & 15);
        else { int r2 = r - I_; pr = 32 * (r2 >> 4) + 16 + (r2 & 15); }
        const float4* s = (const float4*)src + 2 * (size_t)i;
        float4 a = s[0], b = s[1];
        uint4 o;
        o.x = pack2(a.x, a.y);
        o.y = pack2(a.z, a.w);
        o.z = pack2(b.x, b.y);
        o.w = pack2(b.z, b.w);
        *(uint4*)(dst + ((size_t)e * TWOI_ + pr) * H_ + cg * 8) = o;
    }
}

// ---------------------------------------------------------------------------
// Tiled MFMA GEMM, 128x128 tile, BK=32, 4 waves (2x2 of 64x64).
// Block work comes from sched[blockIdx.x] (XCD-pinned: blockIdx%8 = XCD).
// MODE 0: A gathered by token_ids; epilogue = SwiGLU(pairs) -> Hb bf16 [rows,I]
// MODE 1: A direct rows; epilogue = raw bf16 -> Y [rows, NCOLS]
// B is [E][NCOLS][KDIM] bf16 row-major (B^T form, k contiguous)
// ---------------------------------------------------------------------------
template <int NCOLS, int KDIM, int MODE>
__global__ __launch_bounds__(256) void moe_gemm(
    const ushort_t* __restrict__ A, const ushort_t* __restrict__ Bw,
    const int4* __restrict__ sched, const int* __restrict__ token_ids,
    ushort_t* __restrict__ Obf) {
    __shared__ ushort_t As[128 * 32];
    __shared__ ushort_t Bs[128 * 32];
    const int4 sc = sched[blockIdx.x];
    const int e = sc.x;
    if (e < 0) return;
    const int row0 = sc.y;
    const int n0 = sc.z * 128;
    const int mrows = sc.w;
    const int tid = threadIdx.x;
    const int lane = tid & 63, wid = tid >> 6;
    const int wr = wid >> 1, wc = wid & 1;

    // staging: chunk c (of 8) = 16 rows x 32 cols; wave wid handles chunks 2w,2w+1
    const int c0 = wid * 2, c1 = wid * 2 + 1;
    const int ra0 = c0 * 16 + (lane >> 2);
    const int ra1 = c1 * 16 + (lane >> 2);
    const int kc = (lane & 3) * 8;
    const int rg0 = row0 + min(ra0, mrows - 1);
    const int rg1 = row0 + min(ra1, mrows - 1);
    const long arow0 = (MODE == 0) ? (long)token_ids[rg0] : (long)rg0;
    const long arow1 = (MODE == 0) ? (long)token_ids[rg1] : (long)rg1;
    const ushort_t* ap0 = A + arow0 * KDIM + kc;
    const ushort_t* ap1 = A + arow1 * KDIM + kc;
    const ushort_t* Be = Bw + (size_t)e * NCOLS * KDIM;
    const ushort_t* bp0 = Be + (size_t)(n0 + ra0) * KDIM + kc;
    const ushort_t* bp1 = Be + (size_t)(n0 + ra1) * KDIM + kc;
    ushort_t* as0 = As + c0 * 512;
    ushort_t* as1 = As + c1 * 512;
    ushort_t* bs0 = Bs + c0 * 512;
    ushort_t* bs1 = Bs + c1 * 512;

    f32x4 acc[4][4];
#pragma unroll
    for (int i = 0; i < 4; i++)
#pragma unroll
        for (int j = 0; j < 4; j++) acc[i][j] = (f32x4){0.f, 0.f, 0.f, 0.f};

    for (int k = 0; k < KDIM; k += 32) {
        __syncthreads();   // previous iter's LDS reads complete
        gl2lds16(ap0, as0);
        gl2lds16(ap1, as1);
        gl2lds16(bp0, bs0);
        gl2lds16(bp1, bs1);
        ap0 += 32; ap1 += 32; bp0 += 32; bp1 += 32;
        __syncthreads();   // vmcnt drain -> LDS tiles ready
        short8 af[4], bf[4];
        const int fr = lane & 15, fq = (lane >> 4) * 8;
#pragma unroll
        for (int mt = 0; mt < 4; mt++)
            af[mt] = *(const short8*)(As + (wr * 64 + mt * 16 + fr) * 32 + fq);
#pragma unroll
        for (int nt = 0; nt < 4; nt++)
            bf[nt] = *(const short8*)(Bs + (wc * 64 + nt * 16 + fr) * 32 + fq);
#pragma unroll
        for (int mt = 0; mt < 4; mt++)
#pragma unroll
            for (int nt = 0; nt < 4; nt++)
                acc[mt][nt] = __builtin_amdgcn_mfma_f32_16x16x32_bf16(af[mt], bf[nt], acc[mt][nt], 0, 0, 0);
    }

    // epilogue: C/D layout col=lane&15, row=(lane>>4)*4+reg
    const int quad = lane >> 4, tn = lane & 15;
    if (MODE == 0) {
        // nt even = gate, nt odd = up (same lane); Hb col = (n0+wc*64)/2 + j*16 + tn
        const int hbase = ((n0 + wc * 64) >> 1) + tn;
#pragma unroll
        for (int mt = 0; mt < 4; mt++) {
#pragma unroll
            for (int reg = 0; reg < 4; reg++) {
                const int rl = wr * 64 + mt * 16 + quad * 4 + reg;
                if (rl < mrows) {
                    ushort_t* dst = Obf + (size_t)(row0 + rl) * I_ + hbase;
#pragma unroll
                    for (int j = 0; j < 2; j++) {
                        float g = acc[mt][2 * j][reg];
                        float u = acc[mt][2 * j + 1][reg];
                        float h = g / (1.f + __expf(-g)) * u;
                        dst[j * 16] = f2bf(h);
                    }
                }
            }
        }
    } else {
#pragma unroll
        for (int mt = 0; mt < 4; mt++) {
#pragma unroll
            for (int reg = 0; reg < 4; reg++) {
                const int rl = wr * 64 + mt * 16 + quad * 4 + reg;
                if (rl < mrows) {
                    ushort_t* dst = Obf + (size_t)(row0 + rl) * NCOLS + n0 + wc * 64 + tn;
#pragma unroll
                    for (int nt = 0; nt < 4; nt++) dst[nt * 16] = f2bf(acc[mt][nt][reg]);
                }
            }
        }
    }
}

// ---------------------------------------------------------------------------
// Combine: out[t,:] = sum_k wts[t,k] * Y[row_of_slot[t*K+k], :]   (fp32 out)
// ---------------------------------------------------------------------------
__global__ void combine_kernel(const ushort_t* __restrict__ Y,
                               const int* __restrict__ row_of_slot,
                               const float* __restrict__ wts,
                               float* __restrict__ out) {
    const int n8 = T_ * (H_ / 8);
    int i = blockIdx.x * blockDim.x + threadIdx.x;
    const int stride = gridDim.x * blockDim.x;
    for (; i < n8; i += stride) {
        const int t = i / (H_ / 8);
        const int c = (i % (H_ / 8)) * 8;
        const int r0 = row_of_slot[2 * t], r1 = row_of_slot[2 * t + 1];
        const float w0 = wts[2 * t], w1 = wts[2 * t + 1];
        const uint4 y0 = *(const uint4*)(Y + (size_t)r0 * H_ + c);
        const uint4 y1 = *(const uint4*)(Y + (size_t)r1 * H_ + c);
        const uint_t a[4] = {y0.x, y0.y, y0.z, y0.w};
        const uint_t b[4] = {y1.x, y1.y, y1.z, y1.w};
        float o[8];
#pragma unroll
        for (int j = 0; j < 4; j++) {
            o[2 * j]     = w0 * bflo(a[j]) + w1 * bflo(b[j]);
            o[2 * j + 1] = w0 * bfhi(a[j]) + w1 * bfhi(b[j]);
        }
        float4* dst = (float4*)(out + (size_t)t * H_ + c);
        dst[0] = make_float4(o[0], o[1], o[2], o[3]);
        dst[1] = make_float4(o[4], o[5], o[6], o[7]);
    }
}

// ---------------------------------------------------------------------------
extern "C" void kernel_launch(void* const* d_in, const int* in_sizes, int n_in,
                              void* d_out, int out_size, void* d_ws, size_t ws_size,
                              hipStream_t stream) {
    const float* hidden = (const float*)d_in[0];
    const int* topk_idx = (const int*)d_in[1];
    const float* topk_w = (const float*)d_in[2];
    const float* w_gu = (const float*)d_in[3];
    const float* w_d = (const float*)d_in[4];
    float* out = (float*)d_out;

    // workspace layout (bytes)
    char* ws = (char*)d_ws;
    int* token_ids = (int*)ws;                                 // 64 KiB
    int* row_of_slot = (int*)(ws + 65536);                     // 64 KiB
    int4* sched1 = (int4*)(ws + 131072);                       // 8*CAP1*16 = 90112 B
    int4* sched2 = (int4*)(ws + 131072 + 8 * CAP1 * 16);       // 8*CAP2*16 = 65536 B
    char* big = ws + 131072 + 8 * (CAP1 + CAP2) * 16;
    ushort_t* Xb = (ushort_t*)big;                             // T*H bf16      = 33.6 MB
    ushort_t* Wgu = Xb + (size_t)T_ * H_;                      // E*2I*H bf16   = 184.6 MB
    ushort_t* Wd = Wgu + (size_t)E_ * TWOI_ * H_;              // E*H*I bf16    = 92.3 MB
    ushort_t* Hb = Wd + (size_t)E_ * H_ * I_;                  // TK*I bf16     = 46.2 MB
    ushort_t* Y = Hb + (size_t)TK_ * I_;                       // TK*H bf16     = 67.1 MB

    routing_kernel<<<1, 1024, 0, stream>>>(topk_idx, token_ids, row_of_slot, sched1, sched2);

    f2bf_kernel<<<4096, 256, 0, stream>>>(hidden, Xb, (int)((size_t)T_ * H_ / 8));
    f2bf_gu_kernel<<<8192, 256, 0, stream>>>(w_gu, Wgu);
    f2bf_kernel<<<8192, 256, 0, stream>>>(w_d, Wd, (int)((size_t)E_ * H_ * I_ / 8));

    // GEMM1: [rows x H] @ Wgu^T -> SwiGLU -> Hb
    moe_gemm<TWOI_, H_, 0><<<8 * CAP1, 256, 0, stream>>>(
        Xb, Wgu, sched1, token_ids, Hb);

    // GEMM2: [rows x I] @ Wd^T -> Y
    moe_gemm<H_, I_, 1><<<8 * CAP2, 256, 0, stream>>>(
        Hb, Wd, sched2, token_ids, Y);

    combine_kernel<<<4096, 256, 0, stream>>>(Y, row_of_slot, topk_w, out);
}